// Round 9
// baseline (1957.530 us; speedup 1.0000x reference)
//
#include <hip/hip_runtime.h>

#define NNODES 100000
#define NEDGES 300000
#define KF     1433
#define KP     1536   // 24*64, zero-padded tail
#define HID    16
#define NC     7
#define ROWS   4                 // rows per wave-group: acc[4][16]=64 VGPR
#define NGRP   (NNODES / ROWS)   // 25000 groups, exact -> no row guards
#define NFAT   5                 // fat its: k = 4*lane + 256*it, covers k<1280
#define NTAIL  3                 // scalar its: k = 1280 + lane + 64*t, guarded

// ---------------------------------------------------------------------------
// Kernel A: y = x @ w1 (fp32), agg = (1+eps)*y.
// ROOT CAUSE (r8 counters): acc[8][16]=128 VGPR makes the compiler either
// spill (r7: +prefetch -> 5.5 GB scratch) or silently J-CHUNK the loop,
// re-reading x ~16x through L2 (r8: VGPR=116 < acc alone, FETCH=293MB < x,
// dur ~= L2-BW model). Fix: acc[4][16]=64 so the written loop survives.
// ILP via float4 x-loads (4KB/wave in flight) + ds_read_b128 W-reads.
// Other invariants: fp32 W1 only (eps=100 amplifies quant err 101x, r6);
// 512-thread blocks only (1024 pins VGPR=64, r2-4); no K-split (r5).
// ---------------------------------------------------------------------------
__global__ __launch_bounds__(512) void gemm_xw1(const float* __restrict__ x,
                                                const float* __restrict__ w1,
                                                const float* __restrict__ epsp,
                                                float* __restrict__ y,
                                                float* __restrict__ agg) {
    __shared__ float w1t[HID * KP];  // [j][k], 96 KB, zero-padded past KF

    const int tid = threadIdx.x;

    for (int k = tid; k < KP; k += 512) {
        if (k < KF) {
            const float* r = w1 + k * HID;
            #pragma unroll
            for (int j = 0; j < HID; ++j) w1t[j * KP + k] = r[j];
        } else {
            #pragma unroll
            for (int j = 0; j < HID; ++j) w1t[j * KP + k] = 0.f;
        }
    }
    __syncthreads();

    const int wave = tid >> 6;
    const int lane = tid & 63;
    const float co = 1.f + epsp[0];
    const int wid  = blockIdx.x * 8 + wave;   // 2048 waves
    // element kept by lane after the 4 halving steps: bitrev4(lane&15)
    const int jout = ((lane & 1) << 3) | ((lane & 2) << 1) | ((lane & 4) >> 1) | ((lane & 8) >> 3);

    // contiguous balanced group range (2048 waves over 25000 groups)
    const int g0 = (int)(((long long)wid       * NGRP) >> 11);
    const int g1 = (int)(((long long)(wid + 1) * NGRP) >> 11);

    for (int g = g0; g < g1; ++g) {
        const int base = g * ROWS;           // always base+3 < NNODES
        const float* px = x + (size_t)base * KF;

        float acc[ROWS][HID];
        #pragma unroll
        for (int r = 0; r < ROWS; ++r)
            #pragma unroll
            for (int j = 0; j < HID; ++j) acc[r][j] = 0.f;

        // ---- 5 fat iterations: k = 4*lane + 256*it  (k <= 1279 < KF) ----
        #pragma unroll
        for (int it = 0; it < NFAT; ++it) {
            const int k0 = 4 * lane + 256 * it;
            float4 xv[ROWS];
            #pragma unroll
            for (int r = 0; r < ROWS; ++r)
                xv[r] = *(const float4*)(px + (size_t)r * KF + k0);
            #pragma unroll
            for (int j = 0; j < HID; ++j) {
                const float4 wq = *(const float4*)&w1t[j * KP + k0];
                #pragma unroll
                for (int r = 0; r < ROWS; ++r) {
                    acc[r][j] += xv[r].x * wq.x;
                    acc[r][j] += xv[r].y * wq.y;
                    acc[r][j] += xv[r].z * wq.z;
                    acc[r][j] += xv[r].w * wq.w;
                }
            }
        }

        // ---- 3 scalar tail its: k = 1280 + lane + 64*t, guarded ----
        #pragma unroll
        for (int t = 0; t < NTAIL; ++t) {
            const int k = 1280 + lane + 64 * t;   // <= 1471 < KP
            const bool ok = (k < KF);
            float xv[ROWS];
            #pragma unroll
            for (int r = 0; r < ROWS; ++r)
                xv[r] = ok ? px[(size_t)r * KF + k] : 0.f;
            #pragma unroll
            for (int j = 0; j < HID; ++j) {
                const float wv = w1t[j * KP + k];   // zero past KF
                #pragma unroll
                for (int r = 0; r < ROWS; ++r) acc[r][j] += xv[r] * wv;
            }
        }

        // Halving transpose-reduce: 16 vals x 64 lanes
        #pragma unroll
        for (int r = 0; r < ROWS; ++r) {
            float v[HID];
            #pragma unroll
            for (int j = 0; j < HID; ++j) v[j] = acc[r][j];
            #pragma unroll
            for (int s = 0; s < 4; ++s) {
                const int d    = 1 << s;
                const int half = 8 >> s;
                const int sel  = (lane >> s) & 1;
                #pragma unroll
                for (int m = 0; m < half; ++m) {
                    const float send = sel ? v[m] : v[m + half];
                    const float keep = sel ? v[m + half] : v[m];
                    v[m] = keep + __shfl_xor(send, d);
                }
            }
            float tsum = v[0];
            tsum += __shfl_xor(tsum, 16);
            tsum += __shfl_xor(tsum, 32);
            if (lane < HID) {
                const size_t o = (size_t)(base + r) * HID + jout;
                y[o]   = tsum;
                agg[o] = co * tsum;   // (1+eps)*y folded in; scatter adds on top
            }
        }
    }
}

// ---------------------------------------------------------------------------
// Kernel B: agg[dst] += y[src]  (thread per (edge, j))
// ---------------------------------------------------------------------------
__global__ __launch_bounds__(256) void scatter_add(const int* __restrict__ ei,
                                                   const float* __restrict__ y,
                                                   float* __restrict__ agg) {
    const int t = blockIdx.x * 256 + threadIdx.x;
    const int e = t >> 4;
    const int j = t & 15;
    if (e < NEDGES) {
        const int s = ei[e];           // src
        const int d = ei[NEDGES + e];  // dst
        atomicAdd(agg + d * HID + j, y[s * HID + j]);
    }
}

// ---------------------------------------------------------------------------
// Kernel C: out = sigmoid(relu(agg + b1) @ w2 + b2)   (agg already has eps term)
// ---------------------------------------------------------------------------
__global__ __launch_bounds__(256) void mlp_tail(const float* __restrict__ agg,
                                                const float* __restrict__ b1,
                                                const float* __restrict__ w2,
                                                const float* __restrict__ b2,
                                                float* __restrict__ out) {
    __shared__ float sw2[HID * NC];
    __shared__ float sb1[HID];
    __shared__ float sb2[NC];

    const int t = threadIdx.x;
    if (t < HID * NC) sw2[t] = w2[t];
    if (t < HID)      sb1[t] = b1[t];
    if (t < NC)       sb2[t] = b2[t];
    __syncthreads();

    const int i = blockIdx.x * 256 + t;
    if (i >= NNODES) return;

    const float4* a4 = (const float4*)(agg + (size_t)i * HID);

    float h[HID];
    #pragma unroll
    for (int q = 0; q < 4; ++q) {
        const float4 av = a4[q];
        h[q * 4 + 0] = fmaxf(av.x + sb1[q * 4 + 0], 0.f);
        h[q * 4 + 1] = fmaxf(av.y + sb1[q * 4 + 1], 0.f);
        h[q * 4 + 2] = fmaxf(av.z + sb1[q * 4 + 2], 0.f);
        h[q * 4 + 3] = fmaxf(av.w + sb1[q * 4 + 3], 0.f);
    }

    #pragma unroll
    for (int c = 0; c < NC; ++c) {
        float s = sb2[c];
        #pragma unroll
        for (int j = 0; j < HID; ++j) s += h[j] * sw2[j * NC + c];
        out[(size_t)i * NC + c] = 1.f / (1.f + __expf(-s));
    }
}

// ---------------------------------------------------------------------------
extern "C" void kernel_launch(void* const* d_in, const int* in_sizes, int n_in,
                              void* d_out, int out_size, void* d_ws, size_t ws_size,
                              hipStream_t stream) {
    const float* x   = (const float*)d_in[0];
    const int*   ei  = (const int*)d_in[1];
    const float* w1  = (const float*)d_in[2];
    const float* b1  = (const float*)d_in[3];
    const float* w2  = (const float*)d_in[4];
    const float* b2  = (const float*)d_in[5];
    const float* eps = (const float*)d_in[6];
    float* out = (float*)d_out;

    const size_t NY = (size_t)NNODES * HID;
    float* y   = (float*)d_ws;   // 6.4 MB
    float* agg = y + NY;         // 6.4 MB

    gemm_xw1<<<256, 512, 0, stream>>>(x, w1, eps, y, agg);
    scatter_add<<<(NEDGES * 16 + 255) / 256, 256, 0, stream>>>(ei, y, agg);
    mlp_tail<<<(NNODES + 255) / 256, 256, 0, stream>>>(agg, b1, w2, b2, out);
}